// Round 1
// baseline (25.907 us; speedup 1.0000x reference)
//
#include <hip/hip_runtime.h>

#define NPIX 4
#define R_MAX 128

__global__ __launch_bounds__(256) void rbf_kernel(
    const float* __restrict__ centers,   // (I, R, 2)
    const float* __restrict__ covs,      // (I, R, 3)
    const float* __restrict__ amps,      // (I, R)
    const float* __restrict__ grid,      // (P, 2)
    float* __restrict__ out,             // (I, P)
    int R, int P, int blocksPerImage)
{
    // Per-RBF polynomial constants, pre-scaled by -0.5*log2(e):
    // q' = sa*x^2 + sb*y^2 + sc*x*y + k1*x + k2*y + k0 ; contrib = amp * exp2(q')
    __shared__ float4 s_c[R_MAX][2];

    const int img   = blockIdx.x / blocksPerImage;
    const int chunk = blockIdx.x % blocksPerImage;
    const int base  = chunk * (256 * NPIX);

    constexpr float S = -0.72134752044448170f;  // -0.5 * log2(e)

    for (int r = threadIdx.x; r < R; r += 256) {
        const float2 cc = *(const float2*)(centers + (size_t)(img * R + r) * 2);
        const float* cv = covs + (size_t)(img * R + r) * 3;
        const float a = cv[0], b = cv[1], c = cv[2];
        const float amp = amps[img * R + r];
        const float sa = a * S;
        const float sb = b * S;
        const float sc = 2.0f * c * S;
        const float k1 = -2.0f * (a * cc.x + c * cc.y) * S;
        const float k2 = -2.0f * (b * cc.y + c * cc.x) * S;
        const float k0 = (a * cc.x * cc.x + b * cc.y * cc.y + 2.0f * c * cc.x * cc.y) * S;
        s_c[r][0] = make_float4(sa, sb, sc, k1);
        s_c[r][1] = make_float4(k2, k0, amp, 0.0f);
    }
    __syncthreads();

    float gx[NPIX], gy[NPIX], X[NPIX], Y[NPIX], XY[NPIX], z[NPIX];
    #pragma unroll
    for (int k = 0; k < NPIX; ++k) {
        const int p = base + k * 256 + (int)threadIdx.x;
        float2 g = make_float2(0.0f, 0.0f);
        if (p < P) g = *(const float2*)(grid + (size_t)p * 2);
        gx[k] = g.x; gy[k] = g.y;
        X[k]  = g.x * g.x;
        Y[k]  = g.y * g.y;
        XY[k] = g.x * g.y;
        z[k]  = 0.0f;
    }

    for (int r = 0; r < R; ++r) {
        const float4 c0 = s_c[r][0];
        const float4 c1 = s_c[r][1];
        #pragma unroll
        for (int k = 0; k < NPIX; ++k) {
            float t = fmaf(c0.x, X[k],
                      fmaf(c0.y, Y[k],
                      fmaf(c0.z, XY[k],
                      fmaf(c0.w, gx[k],
                      fmaf(c1.x, gy[k], c1.y)))));
            float e;
            asm("v_exp_f32 %0, %1" : "=v"(e) : "v"(t));   // exp2(t)
            z[k] = fmaf(c1.z, e, z[k]);
        }
    }

    #pragma unroll
    for (int k = 0; k < NPIX; ++k) {
        const int p = base + k * 256 + (int)threadIdx.x;
        if (p < P) {
            const float ez = __expf(-z[k]);               // sigmoid
            out[(size_t)img * P + p] = 1.0f / (1.0f + ez);
        }
    }
}

extern "C" void kernel_launch(void* const* d_in, const int* in_sizes, int n_in,
                              void* d_out, int out_size, void* d_ws, size_t ws_size,
                              hipStream_t stream) {
    const float* centers = (const float*)d_in[0];
    const float* covs    = (const float*)d_in[1];
    const float* amps    = (const float*)d_in[2];
    const float* grid    = (const float*)d_in[3];
    float* out = (float*)d_out;

    const int P = in_sizes[3] / 2;        // grid points (rows*cols)
    const int I = out_size / P;           // images
    const int R = in_sizes[2] / I;        // RBFs per image (amps = I*R)

    const int bpi = (P + 256 * NPIX - 1) / (256 * NPIX);
    rbf_kernel<<<I * bpi, 256, 0, stream>>>(centers, covs, amps, grid, out, R, P, bpi);
}

// Round 2
// 22.776 us; speedup vs baseline: 1.1375x; 1.1375x over previous
//
#include <hip/hip_runtime.h>

#define NPIX 2
#define R_MAX 128

__global__ __launch_bounds__(256) void rbf_kernel(
    const float* __restrict__ centers,   // (I, R, 2)
    const float* __restrict__ covs,      // (I, R, 3)
    const float* __restrict__ amps,      // (I, R)
    const float* __restrict__ grid,      // (P, 2)
    float* __restrict__ out,             // (I, P)
    int R, int P, int blocksPerImage)
{
    // Per-RBF polynomial constants, pre-scaled by -0.5*log2(e):
    // q' = sa*x^2 + sb*y^2 + sc*x*y + k1*x + k2*y + k0 ; contrib = amp * exp2(q')
    __shared__ float4 s_c[R_MAX][2];

    const int img   = blockIdx.x / blocksPerImage;
    const int chunk = blockIdx.x % blocksPerImage;
    const int base  = chunk * (256 * NPIX);

    constexpr float S = -0.72134752044448170f;  // -0.5 * log2(e)

    for (int r = threadIdx.x; r < R; r += 256) {
        const float2 cc = *(const float2*)(centers + (size_t)(img * R + r) * 2);
        const float* cv = covs + (size_t)(img * R + r) * 3;
        const float a = cv[0], b = cv[1], c = cv[2];
        const float amp = amps[img * R + r];
        const float sa = a * S;
        const float sb = b * S;
        const float sc = 2.0f * c * S;
        const float k1 = -2.0f * (a * cc.x + c * cc.y) * S;
        const float k2 = -2.0f * (b * cc.y + c * cc.x) * S;
        const float k0 = (a * cc.x * cc.x + b * cc.y * cc.y + 2.0f * c * cc.x * cc.y) * S;
        s_c[r][0] = make_float4(sa, sb, sc, k1);
        s_c[r][1] = make_float4(k2, k0, amp, 0.0f);
    }
    __syncthreads();

    float gx[NPIX], gy[NPIX], X[NPIX], Y[NPIX], XY[NPIX];
    float zA[NPIX], zB[NPIX];
    #pragma unroll
    for (int k = 0; k < NPIX; ++k) {
        const int p = base + k * 256 + (int)threadIdx.x;
        float2 g = make_float2(0.0f, 0.0f);
        if (p < P) g = *(const float2*)(grid + (size_t)p * 2);
        gx[k] = g.x; gy[k] = g.y;
        X[k]  = g.x * g.x;
        Y[k]  = g.y * g.y;
        XY[k] = g.x * g.y;
        zA[k] = 0.0f; zB[k] = 0.0f;
    }

    #pragma unroll 2
    for (int r = 0; r < R; r += 2) {
        const float4 a0 = s_c[r][0];
        const float4 a1 = s_c[r][1];
        const float4 b0 = s_c[r + 1][0];
        const float4 b1 = s_c[r + 1][1];
        #pragma unroll
        for (int k = 0; k < NPIX; ++k) {
            float t0 = fmaf(a0.x, X[k],
                       fmaf(a0.y, Y[k],
                       fmaf(a0.z, XY[k],
                       fmaf(a0.w, gx[k],
                       fmaf(a1.x, gy[k], a1.y)))));
            float t1 = fmaf(b0.x, X[k],
                       fmaf(b0.y, Y[k],
                       fmaf(b0.z, XY[k],
                       fmaf(b0.w, gx[k],
                       fmaf(b1.x, gy[k], b1.y)))));
            float e0, e1;
            asm("v_exp_f32 %0, %1" : "=v"(e0) : "v"(t0));   // exp2(t0)
            asm("v_exp_f32 %0, %1" : "=v"(e1) : "v"(t1));   // exp2(t1)
            zA[k] = fmaf(a1.z, e0, zA[k]);
            zB[k] = fmaf(b1.z, e1, zB[k]);
        }
    }

    #pragma unroll
    for (int k = 0; k < NPIX; ++k) {
        const int p = base + k * 256 + (int)threadIdx.x;
        if (p < P) {
            const float z = zA[k] + zB[k];
            const float ez = __expf(-z);                    // sigmoid
            out[(size_t)img * P + p] = 1.0f / (1.0f + ez);
        }
    }
}

extern "C" void kernel_launch(void* const* d_in, const int* in_sizes, int n_in,
                              void* d_out, int out_size, void* d_ws, size_t ws_size,
                              hipStream_t stream) {
    const float* centers = (const float*)d_in[0];
    const float* covs    = (const float*)d_in[1];
    const float* amps    = (const float*)d_in[2];
    const float* grid    = (const float*)d_in[3];
    float* out = (float*)d_out;

    const int P = in_sizes[3] / 2;        // grid points (rows*cols)
    const int I = out_size / P;           // images
    const int R = in_sizes[2] / I;        // RBFs per image (amps = I*R)

    const int bpi = (P + 256 * NPIX - 1) / (256 * NPIX);
    rbf_kernel<<<I * bpi, 256, 0, stream>>>(centers, covs, amps, grid, out, R, P, bpi);
}